// Round 1
// baseline (1180.130 us; speedup 1.0000x reference)
//
#include <hip/hip_runtime.h>
#include <hip/hip_bf16.h>
#include <math.h>

#define B_DIM   4
#define N_DIM   4096
#define D_MODEL 1024
#define D_LOW   32
#define NPAIR   496          // 32*31/2
#define NROWS   (B_DIM * N_DIM)

// ---------------------------------------------------------------------------
// K1: z = x @ W_red + b_red    (M=16384, K=1024, N=32)
// block 256 threads -> 64 rows x 32 cols, K tiled by 64
// ---------------------------------------------------------------------------
__global__ __launch_bounds__(256) void k1_red(const float* __restrict__ x,
                                              const float* __restrict__ Wr,
                                              const float* __restrict__ br,
                                              float* __restrict__ z) {
    __shared__ float xs[64][64];
    __shared__ float ws[64][32];
    const int t   = threadIdx.x;
    const int rb  = blockIdx.x * 64;
    const int col = t & 31;
    const int rg  = t >> 5;                 // 0..7 -> rows rg*8 .. rg*8+7
    float acc[8];
#pragma unroll
    for (int i = 0; i < 8; ++i) acc[i] = 0.f;

    for (int k0 = 0; k0 < D_MODEL; k0 += 64) {
#pragma unroll
        for (int u = 0; u < 4; ++u) {       // 64x64 floats, float4 loads
            int li  = t * 4 + u * 1024;
            int row = li >> 6, kk = li & 63;
            const float4 v = *reinterpret_cast<const float4*>(
                &x[(size_t)(rb + row) * D_MODEL + k0 + kk]);
            *reinterpret_cast<float4*>(&xs[row][kk]) = v;
        }
#pragma unroll
        for (int u = 0; u < 2; ++u) {       // 64x32 floats
            int li = t * 4 + u * 1024;
            int c  = li & 31, kk = li >> 5;
            const float4 v = *reinterpret_cast<const float4*>(
                &Wr[(size_t)(k0 + kk) * D_LOW + c]);
            *reinterpret_cast<float4*>(&ws[kk][c]) = v;
        }
        __syncthreads();
#pragma unroll 8
        for (int kk = 0; kk < 64; ++kk) {
            float w = ws[kk][col];
#pragma unroll
            for (int rr = 0; rr < 8; ++rr) acc[rr] += xs[rg * 8 + rr][kk] * w;
        }
        __syncthreads();
    }
    const float bias = br[col];
#pragma unroll
    for (int rr = 0; rr < 8; ++rr)
        z[(size_t)(rb + rg * 8 + rr) * D_LOW + col] = acc[rr] + bias;
}

// ---------------------------------------------------------------------------
// K2: plucker_avg per row (496 features), averaged over lags {1,2,4,8}
// one block (256 thr) per row; thread handles pair tid and tid+256
// ---------------------------------------------------------------------------
__global__ __launch_bounds__(256) void k2_plucker(const float* __restrict__ z,
                                                  float* __restrict__ pl) {
    const int row = blockIdx.x;
    const int t   = row & (N_DIM - 1);      // position within sequence
    const int tid = threadIdx.x;

    __shared__ float zc[D_LOW];
    __shared__ float zp[4][D_LOW];
    __shared__ float red[4];

    const int w = tid >> 5, c = tid & 31;
    if (w == 0) {
        zc[c] = z[(size_t)row * D_LOW + c];
    } else if (w <= 4) {
        int lag = 1 << (w - 1);
        if (t >= lag) zp[w - 1][c] = z[(size_t)(row - lag) * D_LOW + c];
    }
    __syncthreads();

    // pair (i,j) for k = tid and k = tid+256, triu order
    int i0, j0, i1 = 0, j1 = 0;
    {
        int k = tid, i = 0;
        while (k >= 31 - i) { k -= 31 - i; ++i; }
        i0 = i; j0 = i + 1 + k;
    }
    const bool has1 = (tid < NPAIR - 256);  // tid < 240
    if (has1) {
        int k = tid + 256, i = 0;
        while (k >= 31 - i) { k -= 31 - i; ++i; }
        i1 = i; j1 = i + 1 + k;
    }

    float acc0 = 0.f, acc1 = 0.f, cnt = 0.f;
#pragma unroll
    for (int li = 0; li < 4; ++li) {
        const int lag = 1 << li;            // 1,2,4,8
        if (t < lag) continue;              // block-uniform
        cnt += 1.f;
        float p0 = zc[i0] * zp[li][j0] - zc[j0] * zp[li][i0];
        float p1 = has1 ? (zc[i1] * zp[li][j1] - zc[j1] * zp[li][i1]) : 0.f;
        float ss = p0 * p0 + p1 * p1;
#pragma unroll
        for (int off = 32; off > 0; off >>= 1) ss += __shfl_down(ss, off);
        if ((tid & 63) == 0) red[tid >> 6] = ss;
        __syncthreads();
        float norm = sqrtf(red[0] + red[1] + red[2] + red[3]);
        float sc   = 1.0f / fmaxf(norm, 1e-6f);
        acc0 += p0 * sc;
        acc1 += p1 * sc;
        __syncthreads();
    }
    const float inv = 1.0f / fmaxf(cnt, 1.f);
    pl[(size_t)row * NPAIR + tid] = acc0 * inv;
    if (has1) pl[(size_t)row * NPAIR + 256 + tid] = acc1 * inv;
}

// ---------------------------------------------------------------------------
// K3: g_avg = plucker @ W_exp + b_exp   (M=16384, K=496, N=1024)
// 64x64 tile, BK=16, 256 threads, 4x4 micro-tile
// ---------------------------------------------------------------------------
__global__ __launch_bounds__(256) void k3_exp(const float* __restrict__ pl,
                                              const float* __restrict__ We,
                                              const float* __restrict__ be,
                                              float* __restrict__ g) {
    __shared__ float as[16][68];
    __shared__ float bs[16][68];
    const int t  = threadIdx.x;
    const int tx = t & 15, ty = t >> 4;
    const int nb = blockIdx.x * 64;
    const int mb = blockIdx.y * 64;
    float acc[4][4];
#pragma unroll
    for (int i = 0; i < 4; ++i)
#pragma unroll
        for (int j = 0; j < 4; ++j) acc[i][j] = 0.f;

    for (int k0 = 0; k0 < NPAIR; k0 += 16) {   // 31 tiles exactly
        {
            int li = t * 4;
            int kk = li & 15, row = li >> 4;
            const float4 v = *reinterpret_cast<const float4*>(
                &pl[(size_t)(mb + row) * NPAIR + k0 + kk]);
            as[kk + 0][row] = v.x; as[kk + 1][row] = v.y;
            as[kk + 2][row] = v.z; as[kk + 3][row] = v.w;
        }
        {
            int li = t * 4;
            int n = li & 63, kk = li >> 6;
            const float4 v = *reinterpret_cast<const float4*>(
                &We[(size_t)(k0 + kk) * D_MODEL + nb + n]);
            *reinterpret_cast<float4*>(&bs[kk][n]) = v;
        }
        __syncthreads();
#pragma unroll
        for (int kk = 0; kk < 16; ++kk) {
            float4 a = *reinterpret_cast<const float4*>(&as[kk][ty * 4]);
            float4 b = *reinterpret_cast<const float4*>(&bs[kk][tx * 4]);
            float av[4] = {a.x, a.y, a.z, a.w};
            float bv[4] = {b.x, b.y, b.z, b.w};
#pragma unroll
            for (int i = 0; i < 4; ++i)
#pragma unroll
                for (int j = 0; j < 4; ++j) acc[i][j] += av[i] * bv[j];
        }
        __syncthreads();
    }
#pragma unroll
    for (int i = 0; i < 4; ++i) {
        int r = mb + ty * 4 + i;
#pragma unroll
        for (int j = 0; j < 4; ++j) {
            int cc = nb + tx * 4 + j;
            g[(size_t)r * D_MODEL + cc] = acc[i][j] + be[cc];
        }
    }
}

// ---------------------------------------------------------------------------
// K4: gate = sigmoid([x, g_avg] @ W_gate + b_gate); out = gate*x+(1-gate)*g
// (M=16384, K=2048, N=1024) same tile structure
// ---------------------------------------------------------------------------
__global__ __launch_bounds__(256) void k4_gate(const float* __restrict__ x,
                                               const float* __restrict__ g,
                                               const float* __restrict__ Wg,
                                               const float* __restrict__ bg,
                                               float* __restrict__ out) {
    __shared__ float as[16][68];
    __shared__ float bs[16][68];
    const int t  = threadIdx.x;
    const int tx = t & 15, ty = t >> 4;
    const int nb = blockIdx.x * 64;
    const int mb = blockIdx.y * 64;
    float acc[4][4];
#pragma unroll
    for (int i = 0; i < 4; ++i)
#pragma unroll
        for (int j = 0; j < 4; ++j) acc[i][j] = 0.f;

    for (int k0 = 0; k0 < 2 * D_MODEL; k0 += 16) {
        {
            int li = t * 4;
            int kk = li & 15, row = li >> 4;
            int kg = k0 + kk;
            const float* src = (kg < D_MODEL)
                ? &x[(size_t)(mb + row) * D_MODEL + kg]
                : &g[(size_t)(mb + row) * D_MODEL + (kg - D_MODEL)];
            const float4 v = *reinterpret_cast<const float4*>(src);
            as[kk + 0][row] = v.x; as[kk + 1][row] = v.y;
            as[kk + 2][row] = v.z; as[kk + 3][row] = v.w;
        }
        {
            int li = t * 4;
            int n = li & 63, kk = li >> 6;
            const float4 v = *reinterpret_cast<const float4*>(
                &Wg[(size_t)(k0 + kk) * D_MODEL + nb + n]);
            *reinterpret_cast<float4*>(&bs[kk][n]) = v;
        }
        __syncthreads();
#pragma unroll
        for (int kk = 0; kk < 16; ++kk) {
            float4 a = *reinterpret_cast<const float4*>(&as[kk][ty * 4]);
            float4 b = *reinterpret_cast<const float4*>(&bs[kk][tx * 4]);
            float av[4] = {a.x, a.y, a.z, a.w};
            float bv[4] = {b.x, b.y, b.z, b.w};
#pragma unroll
            for (int i = 0; i < 4; ++i)
#pragma unroll
                for (int j = 0; j < 4; ++j) acc[i][j] += av[i] * bv[j];
        }
        __syncthreads();
    }
#pragma unroll
    for (int i = 0; i < 4; ++i) {
        int r = mb + ty * 4 + i;
#pragma unroll
        for (int j = 0; j < 4; ++j) {
            int cc = nb + tx * 4 + j;
            float s    = acc[i][j] + bg[cc];
            float gate = 1.0f / (1.0f + expf(-s));
            float xv   = x[(size_t)r * D_MODEL + cc];
            float gv   = g[(size_t)r * D_MODEL + cc];
            out[(size_t)r * D_MODEL + cc] = gate * xv + (1.0f - gate) * gv;
        }
    }
}

// ---------------------------------------------------------------------------
extern "C" void kernel_launch(void* const* d_in, const int* in_sizes, int n_in,
                              void* d_out, int out_size, void* d_ws, size_t ws_size,
                              hipStream_t stream) {
    const float* x  = (const float*)d_in[0];
    const float* Wr = (const float*)d_in[1];
    const float* br = (const float*)d_in[2];
    const float* We = (const float*)d_in[3];
    const float* be = (const float*)d_in[4];
    const float* Wg = (const float*)d_in[5];
    const float* bg = (const float*)d_in[6];
    float* out = (float*)d_out;

    float* z  = (float*)d_ws;                          //  16384 x 32
    float* pl = z + (size_t)NROWS * D_LOW;             //  16384 x 496
    float* g  = pl + (size_t)NROWS * NPAIR;            //  16384 x 1024

    k1_red<<<NROWS / 64, 256, 0, stream>>>(x, Wr, br, z);
    k2_plucker<<<NROWS, 256, 0, stream>>>(z, pl);
    dim3 gdim(D_MODEL / 64, NROWS / 64);
    k3_exp<<<gdim, 256, 0, stream>>>(pl, We, be, g);
    k4_gate<<<gdim, 256, 0, stream>>>(x, g, Wg, bg, out);
}

// Round 2
// 275.593 us; speedup vs baseline: 4.2821x; 4.2821x over previous
//
#include <hip/hip_runtime.h>
#include <hip/hip_bf16.h>
#include <math.h>

#define B_DIM   4
#define N_DIM   4096
#define D_MODEL 1024
#define D_LOW   32
#define NPAIR   496          // 32*31/2
#define NROWS   (B_DIM * N_DIM)
#define KPAD3   512          // plucker K padded

typedef __bf16 bf16;
typedef __bf16 bf16x8 __attribute__((ext_vector_type(8)));
typedef __bf16 bf16x4 __attribute__((ext_vector_type(4)));
typedef float  f32x4  __attribute__((ext_vector_type(4)));

#define GLOAD_LDS16(g, l) __builtin_amdgcn_global_load_lds( \
    (__attribute__((address_space(1))) void*)(g),           \
    (__attribute__((address_space(3))) void*)(l), 16, 0, 0)

// ---------------------------------------------------------------------------
// K1: z = x @ W_red + b_red    (M=16384, K=1024, N=32)  -- fp32, small
// ---------------------------------------------------------------------------
__global__ __launch_bounds__(256) void k1_red(const float* __restrict__ x,
                                              const float* __restrict__ Wr,
                                              const float* __restrict__ br,
                                              float* __restrict__ z) {
    __shared__ float xs[64][64];
    __shared__ float ws[64][32];
    const int t   = threadIdx.x;
    const int rb  = blockIdx.x * 64;
    const int col = t & 31;
    const int rg  = t >> 5;
    float acc[8];
#pragma unroll
    for (int i = 0; i < 8; ++i) acc[i] = 0.f;

    for (int k0 = 0; k0 < D_MODEL; k0 += 64) {
#pragma unroll
        for (int u = 0; u < 4; ++u) {
            int li  = t * 4 + u * 1024;
            int row = li >> 6, kk = li & 63;
            const float4 v = *reinterpret_cast<const float4*>(
                &x[(size_t)(rb + row) * D_MODEL + k0 + kk]);
            *reinterpret_cast<float4*>(&xs[row][kk]) = v;
        }
#pragma unroll
        for (int u = 0; u < 2; ++u) {
            int li = t * 4 + u * 1024;
            int c  = li & 31, kk = li >> 5;
            const float4 v = *reinterpret_cast<const float4*>(
                &Wr[(size_t)(k0 + kk) * D_LOW + c]);
            *reinterpret_cast<float4*>(&ws[kk][c]) = v;
        }
        __syncthreads();
#pragma unroll 8
        for (int kk = 0; kk < 64; ++kk) {
            float w = ws[kk][col];
#pragma unroll
            for (int rr = 0; rr < 8; ++rr) acc[rr] += xs[rg * 8 + rr][kk] * w;
        }
        __syncthreads();
    }
    const float bias = br[col];
#pragma unroll
    for (int rr = 0; rr < 8; ++rr)
        z[(size_t)(rb + rg * 8 + rr) * D_LOW + col] = acc[rr] + bias;
}

// ---------------------------------------------------------------------------
// K2: plucker features -> bf16, K padded to 512 with zeros
// ---------------------------------------------------------------------------
__global__ __launch_bounds__(256) void k2_plucker(const float* __restrict__ z,
                                                  bf16* __restrict__ plb) {
    const int row = blockIdx.x;
    const int t   = row & (N_DIM - 1);
    const int tid = threadIdx.x;

    __shared__ float zc[D_LOW];
    __shared__ float zp[4][D_LOW];
    __shared__ float red[4];

    const int w = tid >> 5, c = tid & 31;
    if (w == 0) {
        zc[c] = z[(size_t)row * D_LOW + c];
    } else if (w <= 4) {
        int lag = 1 << (w - 1);
        if (t >= lag) zp[w - 1][c] = z[(size_t)(row - lag) * D_LOW + c];
    }
    __syncthreads();

    int i0, j0, i1 = 0, j1 = 0;
    {
        int k = tid, i = 0;
        while (k >= 31 - i) { k -= 31 - i; ++i; }
        i0 = i; j0 = i + 1 + k;
    }
    const bool has1 = (tid < NPAIR - 256);  // tid < 240
    if (has1) {
        int k = tid + 256, i = 0;
        while (k >= 31 - i) { k -= 31 - i; ++i; }
        i1 = i; j1 = i + 1 + k;
    }

    float acc0 = 0.f, acc1 = 0.f, cnt = 0.f;
#pragma unroll
    for (int li = 0; li < 4; ++li) {
        const int lag = 1 << li;
        if (t < lag) continue;              // block-uniform
        cnt += 1.f;
        float p0 = zc[i0] * zp[li][j0] - zc[j0] * zp[li][i0];
        float p1 = has1 ? (zc[i1] * zp[li][j1] - zc[j1] * zp[li][i1]) : 0.f;
        float ss = p0 * p0 + p1 * p1;
#pragma unroll
        for (int off = 32; off > 0; off >>= 1) ss += __shfl_down(ss, off);
        if ((tid & 63) == 0) red[tid >> 6] = ss;
        __syncthreads();
        float norm = sqrtf(red[0] + red[1] + red[2] + red[3]);
        float sc   = 1.0f / fmaxf(norm, 1e-6f);
        acc0 += p0 * sc;
        acc1 += p1 * sc;
        __syncthreads();
    }
    const float inv = 1.0f / fmaxf(cnt, 1.f);
    plb[(size_t)row * KPAD3 + tid] = (bf16)(acc0 * inv);
    if (has1) plb[(size_t)row * KPAD3 + 256 + tid] = (bf16)(acc1 * inv);
    else      plb[(size_t)row * KPAD3 + 256 + tid] = (bf16)0.f;  // pad 496..511
}

// ---------------------------------------------------------------------------
// cvt_x: fp32 x -> bf16 into xg[:, 0:1024]
// ---------------------------------------------------------------------------
__global__ __launch_bounds__(256) void cvt_x(const float* __restrict__ x,
                                             bf16* __restrict__ xg) {
    size_t o = ((size_t)blockIdx.x * 256 + threadIdx.x) * 4;
    float4 v = *reinterpret_cast<const float4*>(&x[o]);
    size_t row = o >> 10, col = o & 1023;
    bf16x4 b = { (bf16)v.x, (bf16)v.y, (bf16)v.z, (bf16)v.w };
    *reinterpret_cast<bf16x4*>(&xg[row * 2048 + col]) = b;
}

// ---------------------------------------------------------------------------
// transpose+convert: dst[n][k] = (k < Ksrc) ? src[k][n] : 0
// src [Ksrc][1024] f32, dst [1024][Kpad] bf16.  grid (Kpad/32, 1024/32)
// ---------------------------------------------------------------------------
__global__ __launch_bounds__(256) void transpose_cvt(const float* __restrict__ src,
                                                     bf16* __restrict__ dst,
                                                     int Ksrc, int Kpad) {
    __shared__ float tile[32][36];
    const int t  = threadIdx.x;
    const int kb = blockIdx.x * 32;
    const int nb = blockIdx.y * 32;
    int li = t * 4;
    int kl = li >> 5, nl = li & 31;
    float4 v = {0.f, 0.f, 0.f, 0.f};
    if (kb + kl < Ksrc)
        v = *reinterpret_cast<const float4*>(&src[(size_t)(kb + kl) * 1024 + nb + nl]);
    tile[kl][nl + 0] = v.x; tile[kl][nl + 1] = v.y;
    tile[kl][nl + 2] = v.z; tile[kl][nl + 3] = v.w;
    __syncthreads();
    int nl2 = li >> 5, kl2 = li & 31;
    bf16x4 o = { (bf16)tile[kl2 + 0][nl2], (bf16)tile[kl2 + 1][nl2],
                 (bf16)tile[kl2 + 2][nl2], (bf16)tile[kl2 + 3][nl2] };
    *reinterpret_cast<bf16x4*>(&dst[(size_t)(nb + nl2) * Kpad + kb + kl2]) = o;
}

// ---------------------------------------------------------------------------
// MFMA GEMM, m97 structure: 128x128 tile, BK=32, 4 waves 2x2, 4x4 frags.
// A [M][LDA] bf16 row-major; Bt [1024][KDIM] bf16 (= B^T); C = A.B
// GATE=false: write (acc+bias) as bf16 into xg[:, 1024:2048]   (K3)
// GATE=true : gate=sigmoid(acc+bias); out = gate*x+(1-gate)*g  (K4)
// ---------------------------------------------------------------------------
template <int KDIM, int LDA, bool GATE>
__global__ __launch_bounds__(256) void gemm_mfma(const bf16* __restrict__ A,
                                                 const bf16* __restrict__ Bt,
                                                 const float* __restrict__ bias,
                                                 const float* __restrict__ x,
                                                 bf16* __restrict__ xg,
                                                 float* __restrict__ out) {
    __shared__ bf16 As[128 * 32];
    __shared__ bf16 Bs[128 * 32];
    const int t    = threadIdx.x;
    const int mb   = blockIdx.y * 128;
    const int nb   = blockIdx.x * 128;
    const int w    = t >> 6, lane = t & 63;
    const int wr   = w >> 1, wc = w & 1;
    const int l15  = lane & 15, lhi = lane >> 4;

    f32x4 acc[4][4];
#pragma unroll
    for (int mt = 0; mt < 4; ++mt)
#pragma unroll
        for (int nt = 0; nt < 4; ++nt) acc[mt][nt] = (f32x4){0.f, 0.f, 0.f, 0.f};

    const int li0 = t, li1 = t + 256;
    const int r0 = li0 >> 2, c0 = (li0 & 3) * 8;
    const int r1 = li1 >> 2, c1 = (li1 & 3) * 8;

    for (int kb = 0; kb < KDIM; kb += 32) {
        GLOAD_LDS16(A  + (size_t)(mb + r0) * LDA  + kb + c0, As + li0 * 8);
        GLOAD_LDS16(A  + (size_t)(mb + r1) * LDA  + kb + c1, As + li1 * 8);
        GLOAD_LDS16(Bt + (size_t)(nb + r0) * KDIM + kb + c0, Bs + li0 * 8);
        GLOAD_LDS16(Bt + (size_t)(nb + r1) * KDIM + kb + c1, Bs + li1 * 8);
        __syncthreads();
        bf16x8 a[4], b[4];
#pragma unroll
        for (int mt = 0; mt < 4; ++mt)
            a[mt] = *reinterpret_cast<const bf16x8*>(
                As + (wr * 64 + mt * 16 + l15) * 32 + lhi * 8);
#pragma unroll
        for (int nt = 0; nt < 4; ++nt)
            b[nt] = *reinterpret_cast<const bf16x8*>(
                Bs + (wc * 64 + nt * 16 + l15) * 32 + lhi * 8);
#pragma unroll
        for (int mt = 0; mt < 4; ++mt)
#pragma unroll
            for (int nt = 0; nt < 4; ++nt)
                acc[mt][nt] = __builtin_amdgcn_mfma_f32_16x16x32_bf16(
                    a[mt], b[nt], acc[mt][nt], 0, 0, 0);
        __syncthreads();
    }

#pragma unroll
    for (int mt = 0; mt < 4; ++mt) {
#pragma unroll
        for (int nt = 0; nt < 4; ++nt) {
            const int col = nb + wc * 64 + nt * 16 + l15;
            const float bv = bias[col];
#pragma unroll
            for (int r = 0; r < 4; ++r) {
                const int row = mb + wr * 64 + mt * 16 + lhi * 4 + r;
                float v = acc[mt][nt][r] + bv;
                if constexpr (GATE) {
                    float gate = 1.f / (1.f + expf(-v));
                    float xv = x[(size_t)row * D_MODEL + col];
                    float gv = (float)xg[(size_t)row * 2048 + 1024 + col];
                    out[(size_t)row * D_MODEL + col] = gate * xv + (1.f - gate) * gv;
                } else {
                    xg[(size_t)row * 2048 + 1024 + col] = (bf16)v;
                }
            }
        }
    }
}

// ---------------------------------------------------------------------------
extern "C" void kernel_launch(void* const* d_in, const int* in_sizes, int n_in,
                              void* d_out, int out_size, void* d_ws, size_t ws_size,
                              hipStream_t stream) {
    const float* x  = (const float*)d_in[0];
    const float* Wr = (const float*)d_in[1];
    const float* br = (const float*)d_in[2];
    const float* We = (const float*)d_in[3];
    const float* be = (const float*)d_in[4];
    const float* Wg = (const float*)d_in[5];
    const float* bg = (const float*)d_in[6];
    float* out = (float*)d_out;

    char* ws = (char*)d_ws;
    float* z   = (float*)(ws);                          //  2 MB
    bf16* plb  = (bf16*)(ws + (2u << 20));              // 16 MB  [16384][512]
    bf16* xg   = (bf16*)(ws + (18u << 20));             // 64 MB  [16384][2048]
    bf16* WeT  = (bf16*)(ws + (82u << 20));             //  1 MB  [1024][512]
    bf16* WgT  = (bf16*)(ws + (83u << 20));             //  4 MB  [1024][2048]

    k1_red<<<NROWS / 64, 256, 0, stream>>>(x, Wr, br, z);
    cvt_x<<<NROWS * D_MODEL / 4 / 256, 256, 0, stream>>>(x, xg);
    transpose_cvt<<<dim3(KPAD3 / 32, 1024 / 32), 256, 0, stream>>>(We, WeT, NPAIR, KPAD3);
    transpose_cvt<<<dim3(2048 / 32, 1024 / 32), 256, 0, stream>>>(Wg, WgT, 2048, 2048);
    k2_plucker<<<NROWS, 256, 0, stream>>>(z, plb);

    dim3 g3(D_MODEL / 128, NROWS / 128);
    gemm_mfma<KPAD3, KPAD3, false><<<g3, 256, 0, stream>>>(plb, WeT, be, nullptr, xg, nullptr);
    gemm_mfma<2048, 2048, true><<<g3, 256, 0, stream>>>(xg, WgT, bg, x, xg, out);
}

// Round 3
// 198.926 us; speedup vs baseline: 5.9325x; 1.3854x over previous
//
#include <hip/hip_runtime.h>
#include <hip/hip_bf16.h>
#include <math.h>

#define B_DIM   4
#define N_DIM   4096
#define D_MODEL 1024
#define D_LOW   32
#define NPAIR   496          // 32*31/2
#define NROWS   (B_DIM * N_DIM)
#define KPAD3   512          // plucker K padded

typedef __bf16 bf16;
typedef __bf16 bf16x8 __attribute__((ext_vector_type(8)));
typedef __bf16 bf16x4 __attribute__((ext_vector_type(4)));
typedef float  f32x4  __attribute__((ext_vector_type(4)));

#define GLOAD_LDS16(g, l) __builtin_amdgcn_global_load_lds( \
    (__attribute__((address_space(1))) void*)(g),           \
    (__attribute__((address_space(3))) void*)(l), 16, 0, 0)

// ---------------------------------------------------------------------------
// K1: z = x @ W_red + b_red  (M=16384,K=1024,N=32) fp32 + fused x->bf16 write
// ---------------------------------------------------------------------------
__global__ __launch_bounds__(256) void k1_red(const float* __restrict__ x,
                                              const float* __restrict__ Wr,
                                              const float* __restrict__ br,
                                              float* __restrict__ z,
                                              bf16* __restrict__ xg) {
    __shared__ float xs[64][64];
    __shared__ float ws[64][32];
    const int t   = threadIdx.x;
    const int rb  = blockIdx.x * 64;
    const int col = t & 31;
    const int rg  = t >> 5;
    float acc[8];
#pragma unroll
    for (int i = 0; i < 8; ++i) acc[i] = 0.f;

    for (int k0 = 0; k0 < D_MODEL; k0 += 64) {
#pragma unroll
        for (int u = 0; u < 4; ++u) {
            int li  = t * 4 + u * 1024;
            int row = li >> 6, kk = li & 63;
            const float4 v = *reinterpret_cast<const float4*>(
                &x[(size_t)(rb + row) * D_MODEL + k0 + kk]);
            *reinterpret_cast<float4*>(&xs[row][kk]) = v;
            bf16x4 bv = { (bf16)v.x, (bf16)v.y, (bf16)v.z, (bf16)v.w };
            *reinterpret_cast<bf16x4*>(&xg[(size_t)(rb + row) * 2048 + k0 + kk]) = bv;
        }
#pragma unroll
        for (int u = 0; u < 2; ++u) {
            int li = t * 4 + u * 1024;
            int c  = li & 31, kk = li >> 5;
            const float4 v = *reinterpret_cast<const float4*>(
                &Wr[(size_t)(k0 + kk) * D_LOW + c]);
            *reinterpret_cast<float4*>(&ws[kk][c]) = v;
        }
        __syncthreads();
#pragma unroll 8
        for (int kk = 0; kk < 64; ++kk) {
            float w = ws[kk][col];
#pragma unroll
            for (int rr = 0; rr < 8; ++rr) acc[rr] += xs[rg * 8 + rr][kk] * w;
        }
        __syncthreads();
    }
    const float bias = br[col];
#pragma unroll
    for (int rr = 0; rr < 8; ++rr)
        z[(size_t)(rb + rg * 8 + rr) * D_LOW + col] = acc[rr] + bias;
}

// ---------------------------------------------------------------------------
// K2: plucker_avg -> bf16 [row][512].  One wave per row, no barriers.
// Lagrange: ||p_lag||^2 = |zc|^2|zp|^2 - (zc.zp)^2
// Factor:   sum_lag s_lag*(zc_i zp_j - zc_j zp_i) = zc_i w_j - zc_j w_i,
//           w = sum_lag s_lag * zp_lag
// ---------------------------------------------------------------------------
__global__ __launch_bounds__(256) void k2_plucker(const float* __restrict__ z,
                                                  bf16* __restrict__ plb) {
    const int wv   = threadIdx.x >> 6;
    const int lane = threadIdx.x & 63;
    const int row  = blockIdx.x * 4 + wv;
    const int t    = row & (N_DIM - 1);
    const int c    = lane & 31;

    float zc = z[(size_t)row * D_LOW + c];
    float zp[4];
    float red[9];
    red[0] = zc * zc;
#pragma unroll
    for (int li = 0; li < 4; ++li) {
        const int lag = 1 << li;
        zp[li] = (t >= lag) ? z[(size_t)(row - lag) * D_LOW + c] : 0.f;
        red[1 + li] = zc * zp[li];
        red[5 + li] = zp[li] * zp[li];
    }
#pragma unroll
    for (int m = 1; m < 32; m <<= 1) {
#pragma unroll
        for (int i = 0; i < 9; ++i) red[i] += __shfl_xor(red[i], m);
    }
    float cnt = 0.f;
#pragma unroll
    for (int li = 0; li < 4; ++li) cnt += (t >= (1 << li)) ? 1.f : 0.f;
    const float inv = 1.f / fmaxf(cnt, 1.f);

    float w = 0.f;
#pragma unroll
    for (int li = 0; li < 4; ++li) {
        float n2 = fmaxf(red[0] * red[5 + li] - red[1 + li] * red[1 + li], 0.f);
        float nr = sqrtf(n2);
        float s  = (t >= (1 << li)) ? inv / fmaxf(nr, 1e-6f) : 0.f;
        w += s * zp[li];
    }

#pragma unroll
    for (int u = 0; u < 8; ++u) {
        const int k = u * 64 + lane;
        float v = 0.f;
        if (k < NPAIR) {
            int kk = k, i = 0;
            while (kk >= 31 - i) { kk -= 31 - i; ++i; }
            const int j = i + 1 + kk;
            float zci = __shfl(zc, i), zcj = __shfl(zc, j);
            float wi  = __shfl(w, i),  wj  = __shfl(w, j);
            v = zci * wj - zcj * wi;
        }
        plb[(size_t)row * KPAD3 + k] = (bf16)v;
    }
}

// ---------------------------------------------------------------------------
// transpose+convert: dst[n][k] = (k < Ksrc) ? src[k][n] : 0
// ---------------------------------------------------------------------------
__global__ __launch_bounds__(256) void transpose_cvt(const float* __restrict__ src,
                                                     bf16* __restrict__ dst,
                                                     int Ksrc, int Kpad) {
    __shared__ float tile[32][36];
    const int t  = threadIdx.x;
    const int kb = blockIdx.x * 32;
    const int nb = blockIdx.y * 32;
    int li = t * 4;
    int kl = li >> 5, nl = li & 31;
    float4 v = {0.f, 0.f, 0.f, 0.f};
    if (kb + kl < Ksrc)
        v = *reinterpret_cast<const float4*>(&src[(size_t)(kb + kl) * 1024 + nb + nl]);
    tile[kl][nl + 0] = v.x; tile[kl][nl + 1] = v.y;
    tile[kl][nl + 2] = v.z; tile[kl][nl + 3] = v.w;
    __syncthreads();
    int nl2 = li >> 5, kl2 = li & 31;
    bf16x4 o = { (bf16)tile[kl2 + 0][nl2], (bf16)tile[kl2 + 1][nl2],
                 (bf16)tile[kl2 + 2][nl2], (bf16)tile[kl2 + 3][nl2] };
    *reinterpret_cast<bf16x4*>(&dst[(size_t)(nb + nl2) * Kpad + kb + kl2]) = o;
}

// ---------------------------------------------------------------------------
// 256x256 MFMA GEMM, BK=64, 8 waves (2Mx4N), dbuf LDS 128KB, 4 phases/K-tile,
// counted vmcnt, XOR-swizzled LDS (byte ^= (row&7)<<4), XCD block swizzle.
// A [M][KDIM] bf16, Bt [1024][KDIM] bf16.  C = A.Bt^T
// ---------------------------------------------------------------------------
template <int KDIM, bool GATE>
__global__ __launch_bounds__(512, 2) void gemm8(const bf16* __restrict__ A,
                                                const bf16* __restrict__ Bt,
                                                const float* __restrict__ bias,
                                                const float* __restrict__ x,
                                                bf16* __restrict__ xg,
                                                float* __restrict__ out) {
    extern __shared__ char lds[];            // 131072 B: [dbuf][A|B][half][16KB]
    const int t    = threadIdx.x;
    const int w    = t >> 6, lane = t & 63;
    const int wr   = w >> 2, wc = w & 3;     // 2 x 4 wave grid
    const int l15  = lane & 15, lhi = lane >> 4;

    // XCD-bijective swizzle: 256 blocks, 8 XCDs; 32 blocks/XCD share one B panel
    const int fid = blockIdx.x;
    const int swz = (fid & 7) * 32 + (fid >> 3);
    const int nb  = (swz >> 6) * 256;        // 4 N panels
    const int mb  = (swz & 63) * 256;        // 64 M panels

    // staging: thread covers 16B; row = t>>3 (+64*u +128*h), colblk = (t&7)^(row&7)
    const int srow = t >> 3;
    const int scol = ((t & 7) ^ (srow & 7)) * 8;
    const size_t aRow = (size_t)(mb + srow) * KDIM + scol;
    const size_t bRow = (size_t)(nb + srow) * KDIM + scol;
    const int sdst = t * 16;
    char* const ldsA = lds;                  // + d*65536 + h*16384
    char* const ldsB = lds + 32768;

#define STAGE_A(d, h, kb) do { \
    GLOAD_LDS16(A + aRow + (size_t)((h) * 128) * KDIM + (kb),      ldsA + (d) * 65536 + (h) * 16384 + sdst); \
    GLOAD_LDS16(A + aRow + (size_t)((h) * 128 + 64) * KDIM + (kb), ldsA + (d) * 65536 + (h) * 16384 + 8192 + sdst); } while (0)
#define STAGE_B(d, h, kb) do { \
    GLOAD_LDS16(Bt + bRow + (size_t)((h) * 128) * KDIM + (kb),      ldsB + (d) * 65536 + (h) * 16384 + sdst); \
    GLOAD_LDS16(Bt + bRow + (size_t)((h) * 128 + 64) * KDIM + (kb), ldsB + (d) * 65536 + (h) * 16384 + 8192 + sdst); } while (0)

    f32x4 acc[8][4];
#pragma unroll
    for (int i = 0; i < 8; ++i)
#pragma unroll
        for (int j = 0; j < 4; ++j) acc[i][j] = (f32x4){0.f, 0.f, 0.f, 0.f};

    // prologue: stage K-tile 0 (8 loads)
    STAGE_A(0, 0, 0); STAGE_A(0, 1, 0); STAGE_B(0, 0, 0); STAGE_B(0, 1, 0);

    const int NT = KDIM / 64;
    int cur = 0;
    bf16x8 afr[4][2], bfr[4][2];
    const int swx = (l15 & 7) << 4;          // read-side XOR

    for (int kt = 0; kt < NT; ++kt) {
        const int  kb2 = (kt + 1) * 64;
        const bool pre = (kt + 1 < NT);
        const char* Ab = ldsA + cur * 65536 + wr * 16384;
        const char* Bb = ldsB + cur * 65536 + (wc >> 1) * 16384;

        // ---- phase 0: stage A-half0(next) | wait tile | read B all + A mq=0 | q(0,*lo)
        if (pre) { STAGE_A(cur ^ 1, 0, kb2);
                   asm volatile("s_waitcnt vmcnt(2)" ::: "memory"); }
        else     { asm volatile("s_waitcnt vmcnt(0)" ::: "memory"); }
        asm volatile("s_barrier" ::: "memory");
#pragma unroll
        for (int nf = 0; nf < 4; ++nf)
#pragma unroll
            for (int ks = 0; ks < 2; ++ks) {
                int lin = (wc & 1) * 8192 + nf * 2048 + l15 * 128 + ks * 64 + lhi * 16;
                bfr[nf][ks] = *reinterpret_cast<const bf16x8*>(Bb + (lin ^ swx));
            }
#pragma unroll
        for (int mf = 0; mf < 4; ++mf)
#pragma unroll
            for (int ks = 0; ks < 2; ++ks) {
                int lin = mf * 2048 + l15 * 128 + ks * 64 + lhi * 16;
                afr[mf][ks] = *reinterpret_cast<const bf16x8*>(Ab + (lin ^ swx));
            }
        __builtin_amdgcn_s_setprio(1);
#pragma unroll
        for (int mf = 0; mf < 4; ++mf)
#pragma unroll
            for (int nf = 0; nf < 2; ++nf)
#pragma unroll
                for (int ks = 0; ks < 2; ++ks)
                    acc[mf][nf] = __builtin_amdgcn_mfma_f32_16x16x32_bf16(
                        afr[mf][ks], bfr[nf][ks], acc[mf][nf], 0, 0, 0);
        __builtin_amdgcn_s_setprio(0);

        // ---- phase 1: stage A-half1(next) | q(0,*hi)
        if (pre) STAGE_A(cur ^ 1, 1, kb2);
        __builtin_amdgcn_s_setprio(1);
#pragma unroll
        for (int mf = 0; mf < 4; ++mf)
#pragma unroll
            for (int nf = 2; nf < 4; ++nf)
#pragma unroll
                for (int ks = 0; ks < 2; ++ks)
                    acc[mf][nf] = __builtin_amdgcn_mfma_f32_16x16x32_bf16(
                        afr[mf][ks], bfr[nf][ks], acc[mf][nf], 0, 0, 0);
        __builtin_amdgcn_s_setprio(0);

        // ---- phase 2: stage B-half0(next) | read A mq=1 | q(1,*lo)
        if (pre) STAGE_B(cur ^ 1, 0, kb2);
#pragma unroll
        for (int mf = 0; mf < 4; ++mf)
#pragma unroll
            for (int ks = 0; ks < 2; ++ks) {
                int lin = 8192 + mf * 2048 + l15 * 128 + ks * 64 + lhi * 16;
                afr[mf][ks] = *reinterpret_cast<const bf16x8*>(Ab + (lin ^ swx));
            }
        __builtin_amdgcn_s_setprio(1);
#pragma unroll
        for (int mf = 0; mf < 4; ++mf)
#pragma unroll
            for (int nf = 0; nf < 2; ++nf)
#pragma unroll
                for (int ks = 0; ks < 2; ++ks)
                    acc[4 + mf][nf] = __builtin_amdgcn_mfma_f32_16x16x32_bf16(
                        afr[mf][ks], bfr[nf][ks], acc[4 + mf][nf], 0, 0, 0);
        __builtin_amdgcn_s_setprio(0);

        // ---- phase 3: stage B-half1(next) | q(1,*hi)
        if (pre) STAGE_B(cur ^ 1, 1, kb2);
        __builtin_amdgcn_s_setprio(1);
#pragma unroll
        for (int mf = 0; mf < 4; ++mf)
#pragma unroll
            for (int nf = 2; nf < 4; ++nf)
#pragma unroll
                for (int ks = 0; ks < 2; ++ks)
                    acc[4 + mf][nf] = __builtin_amdgcn_mfma_f32_16x16x32_bf16(
                        afr[mf][ks], bfr[nf][ks], acc[4 + mf][nf], 0, 0, 0);
        __builtin_amdgcn_s_setprio(0);
        asm volatile("s_barrier" ::: "memory");   // readers done before next overwrites
        cur ^= 1;
    }
#undef STAGE_A
#undef STAGE_B

    // epilogue
#pragma unroll
    for (int mi = 0; mi < 8; ++mi) {
#pragma unroll
        for (int nf = 0; nf < 4; ++nf) {
            const int col = nb + wc * 64 + nf * 16 + l15;
            const float bv = bias[col];
#pragma unroll
            for (int r = 0; r < 4; ++r) {
                const int row = mb + wr * 128 + mi * 16 + lhi * 4 + r;
                float v = acc[mi][nf][r] + bv;
                if constexpr (GATE) {
                    float gate = 1.f / (1.f + expf(-v));
                    float xv = x[(size_t)row * D_MODEL + col];
                    float gv = (float)xg[(size_t)row * 2048 + 1024 + col];
                    out[(size_t)row * D_MODEL + col] = gate * xv + (1.f - gate) * gv;
                } else {
                    xg[(size_t)row * 2048 + 1024 + col] = (bf16)v;
                }
            }
        }
    }
}

// ---------------------------------------------------------------------------
extern "C" void kernel_launch(void* const* d_in, const int* in_sizes, int n_in,
                              void* d_out, int out_size, void* d_ws, size_t ws_size,
                              hipStream_t stream) {
    const float* x  = (const float*)d_in[0];
    const float* Wr = (const float*)d_in[1];
    const float* br = (const float*)d_in[2];
    const float* We = (const float*)d_in[3];
    const float* be = (const float*)d_in[4];
    const float* Wg = (const float*)d_in[5];
    const float* bg = (const float*)d_in[6];
    float* out = (float*)d_out;

    char* ws = (char*)d_ws;
    float* z   = (float*)(ws);                          //  2 MB
    bf16* plb  = (bf16*)(ws + (2u << 20));              // 16 MB  [16384][512]
    bf16* xg   = (bf16*)(ws + (18u << 20));             // 64 MB  [16384][2048]
    bf16* WeT  = (bf16*)(ws + (82u << 20));             //  1 MB  [1024][512]
    bf16* WgT  = (bf16*)(ws + (83u << 20));             //  4 MB  [1024][2048]

    // allow 128KB dynamic LDS (ignore errors; no-op where unneeded)
    (void)hipFuncSetAttribute(reinterpret_cast<const void*>(&gemm8<KPAD3, false>),
                              hipFuncAttributeMaxDynamicSharedMemorySize, 131072);
    (void)hipFuncSetAttribute(reinterpret_cast<const void*>(&gemm8<2048, true>),
                              hipFuncAttributeMaxDynamicSharedMemorySize, 131072);

    k1_red<<<NROWS / 64, 256, 0, stream>>>(x, Wr, br, z, xg);
    transpose_cvt<<<dim3(KPAD3 / 32, 1024 / 32), 256, 0, stream>>>(We, WeT, NPAIR, KPAD3);
    transpose_cvt<<<dim3(2048 / 32, 1024 / 32), 256, 0, stream>>>(Wg, WgT, 2048, 2048);
    k2_plucker<<<NROWS / 4, 256, 0, stream>>>(z, plb);

    gemm8<KPAD3, false><<<256, 512, 131072, stream>>>(plb, WeT, be, nullptr, xg, nullptr);
    gemm8<2048, true><<<256, 512, 131072, stream>>>(xg, WgT, bg, x, xg, out);
}